// Round 5
// baseline (101.609 us; speedup 1.0000x reference)
//
#include <hip/hip_runtime.h>
#include <hip/hip_fp16.h>

#define B_SZ    16384
#define NNZ_PER 32
#define F_DIM   768
#define H_DIM   512

typedef unsigned int  uint32;
typedef unsigned long long uint64;
typedef unsigned char uchar;

// ---------------------------------------------------------------------------
// fp32 -> fp8 e5m2 (RNE): e5m2 is the top byte of fp16. Decode (byte<<8) is
// exact fp16. Weights ~N(0,0.02): no overflow/subnormal trouble.
// ---------------------------------------------------------------------------
__device__ inline uchar f32_to_e5m2(float x) {
    __half h = __float2half_rn(x);
    unsigned short hb = *(unsigned short*)&h;
    unsigned short lsb = (hb >> 8) & 1;
    hb = (unsigned short)(hb + 0x7F + lsb);   // RNE into top 8 bits
    return (uchar)(hb >> 8);
}

__global__ __launch_bounds__(256) void transpose_convert(
    const float* __restrict__ W, uchar* __restrict__ Wt8)
{
    __shared__ float tile[32][33];
    const int f0 = blockIdx.x * 32;
    const int h0 = blockIdx.y * 32;
    const int tx = threadIdx.x;
    const int ty = threadIdx.y;

#pragma unroll
    for (int i = 0; i < 32; i += 8)
        tile[ty + i][tx] = W[(h0 + ty + i) * F_DIM + f0 + tx];
    __syncthreads();
#pragma unroll
    for (int i = 0; i < 32; i += 8)
        Wt8[(size_t)(f0 + ty + i) * H_DIM + h0 + tx] = f32_to_e5m2(tile[tx][ty + i]);
}

// ---------------------------------------------------------------------------
// Main: R2/R4 structure (1 wave/position, 8 groups x 4 uint4 gathers,
// double-buffered, sched_barrier-pinned) with ALL feature metadata
// batch-preloaded into VGPRs (F[8]) at the prologue. After the prologue the
// gather stream has zero LDS dependencies: addresses come from resident
// registers (1 v_lshl_add each). R1/R3 vs R2/R4 established ~10cyc/VMEM-instr
// TCP cost; the remaining serialization was 8 dependent ds_read_b128 on the
// load path, removed here. launch_bounds (256,5) so the allocator can hold
// metadata + 2-deep buffers (~100 VGPR) without re-serializing the pipeline.
// Accumulation order is bit-identical to R2/R4 (absmax must stay 0.00390625).
// ---------------------------------------------------------------------------
__global__ __launch_bounds__(256, 5) void nnue_fwd(
    const int*   __restrict__ stm_idx,
    const int*   __restrict__ nstm_idx,
    const float* __restrict__ stm_val,
    const float* __restrict__ nstm_val,
    const uchar* __restrict__ Wt8,        // [F][H] e5m2
    const float* __restrict__ b_ft,
    const float* __restrict__ W_out,
    const float* __restrict__ b_out,
    float* __restrict__ out)
{
    const int tid  = threadIdx.x;
    const int w    = tid >> 6;
    const int lane = tid & 63;
    const int half = lane >> 5;
    const int c    = lane & 31;
    const int b    = blockIdx.x * 4 + w;
    const int NNZ  = B_SZ * NNZ_PER;

    // Parity-sorted metadata, split arrays:
    // slot = (k&1)*32 + side*16 + (k>>1); side 0=stm 1=nstm.
    __shared__ uint32 shf[4][64];   // feature index
    __shared__ uint32 shv[4][64];   // half2(v,v)
    {
        const int base = b * NNZ_PER;
        const int k    = lane & 31;
        const int side = lane >> 5;
        int f; float v;
        if (side == 0) { f = stm_idx [NNZ + base + k]; v = stm_val [base + k]; }
        else           { f = nstm_idx[NNZ + base + k]; v = nstm_val[base + k]; }
        const int slot = (k & 1) * 32 + side * 16 + (k >> 1);
        __half2 vv = __float2half2_rn(v);
        shf[w][slot] = (uint32)f;
        shv[w][slot] = *(uint32*)&vv;
    }
    // Producer wave == consumer wave: lgkmcnt ordering suffices, no barrier.

    const uint32 selA = 0x01040004u;   // [0,b0,0,b1] -> half2(h0,h1)
    const uint32 selB = 0x03040204u;   // [0,b2,0,b3] -> half2(h2,h3)
    const uint32 coff = (uint32)c << 4;          // 16 B per c in a 512 B row
    const uint32* fm  = &shf[w][half * 32];
    const uint32* vm  = &shv[w][half * 32];

    // Batch-preload the wave's 32 feature indices into VGPRs: the whole
    // gather stream below depends only on registers, never on LDS.
    uint4 F[8];
#pragma unroll
    for (int q = 0; q < 8; ++q)
        F[q] = *(const uint4*)(fm + 4 * q);

    __half2 z = __float2half2_rn(0.f);
    __half2 sa[8] = {z,z,z,z,z,z,z,z};
    __half2 na[8] = {z,z,z,z,z,z,z,z};

    uint4 bufA[4], bufB[4];

    // Group g (0..3 stm -> sa, 4..7 nstm -> na); metadata quadrant index
    // q = (g>=4?4:0)+(g&3). sched_barrier(0) pins the 4 gathers ABOVE all
    // following code so the double-buffer stays materialized in VGPRs.
#define LOAD_GROUP(g, BUF)                                                    \
    {                                                                         \
        uint4 ff = F[((g) >= 4 ? 4 : 0) + ((g) & 3)];                         \
        BUF[0] = *(const uint4*)(Wt8 + ((ff.x << 9) + coff));                 \
        BUF[1] = *(const uint4*)(Wt8 + ((ff.y << 9) + coff));                 \
        BUF[2] = *(const uint4*)(Wt8 + ((ff.z << 9) + coff));                 \
        BUF[3] = *(const uint4*)(Wt8 + ((ff.w << 9) + coff));                 \
        __builtin_amdgcn_sched_barrier(0);                                    \
    }

#define FMA_GROUP(g, BUF, ACC)                                                \
    {                                                                         \
        uint4 vv4 = *(const uint4*)(vm + ((g) >= 4 ? 16 : 0) + 4 * ((g) & 3));\
        uint32 va[4] = {vv4.x, vv4.y, vv4.z, vv4.w};                          \
        _Pragma("unroll")                                                     \
        for (int i = 0; i < 4; ++i) {                                         \
            uint4 wv = BUF[i];                                                \
            __half2 vv = *(__half2*)&va[i];                                   \
            uint32 p;                                                         \
            p = __builtin_amdgcn_perm(0u, wv.x, selA); ACC[0] = __hfma2(*(__half2*)&p, vv, ACC[0]); \
            p = __builtin_amdgcn_perm(0u, wv.x, selB); ACC[1] = __hfma2(*(__half2*)&p, vv, ACC[1]); \
            p = __builtin_amdgcn_perm(0u, wv.y, selA); ACC[2] = __hfma2(*(__half2*)&p, vv, ACC[2]); \
            p = __builtin_amdgcn_perm(0u, wv.y, selB); ACC[3] = __hfma2(*(__half2*)&p, vv, ACC[3]); \
            p = __builtin_amdgcn_perm(0u, wv.z, selA); ACC[4] = __hfma2(*(__half2*)&p, vv, ACC[4]); \
            p = __builtin_amdgcn_perm(0u, wv.z, selB); ACC[5] = __hfma2(*(__half2*)&p, vv, ACC[5]); \
            p = __builtin_amdgcn_perm(0u, wv.w, selA); ACC[6] = __hfma2(*(__half2*)&p, vv, ACC[6]); \
            p = __builtin_amdgcn_perm(0u, wv.w, selB); ACC[7] = __hfma2(*(__half2*)&p, vv, ACC[7]); \
        }                                                                     \
    }

    LOAD_GROUP(0, bufA);
    LOAD_GROUP(1, bufB);
    FMA_GROUP(0, bufA, sa);  LOAD_GROUP(2, bufA);
    FMA_GROUP(1, bufB, sa);  LOAD_GROUP(3, bufB);
    FMA_GROUP(2, bufA, sa);  LOAD_GROUP(4, bufA);
    FMA_GROUP(3, bufB, sa);  LOAD_GROUP(5, bufB);
    FMA_GROUP(4, bufA, na);  LOAD_GROUP(6, bufA);
    FMA_GROUP(5, bufB, na);  LOAD_GROUP(7, bufB);
    FMA_GROUP(6, bufA, na);
    FMA_GROUP(7, bufB, na);

#undef LOAD_GROUP
#undef FMA_GROUP

    // Epilogue (identical numerics to R2/R4): lane^32 holds the other
    // feature parity for the same h-range; half=0 lanes dot stm vs
    // W_out[0:512), half=1 nstm vs W_out[512:1024); full-wave reduce sums.
    const float4* b4 = (const float4*)(b_ft + c * 16);
    const float4* w4 = (const float4*)(W_out + half * H_DIM + c * 16);
    float4 bv[4]  = {b4[0], b4[1], b4[2], b4[3]};
    float4 wv4[4] = {w4[0], w4[1], w4[2], w4[3]};
    const float* bias = (const float*)bv;
    const float* wo   = (const float*)wv4;

    float dot = 0.f;
#pragma unroll
    for (int k = 0; k < 8; ++k) {
        int ms = *(int*)&sa[k];
        int mn = *(int*)&na[k];
        int os = __shfl_xor(ms, 32, 64);
        int on = __shfl_xor(mn, 32, 64);
        int mm = half ? mn : ms;
        int oo = half ? on : os;
        __half2 mh = *(__half2*)&mm;
        __half2 oh = *(__half2*)&oo;
        float h0 = __low2float(mh)  + __low2float(oh);
        float h1 = __high2float(mh) + __high2float(oh);
        float a0 = fminf(fmaxf(h0 + bias[2 * k],     0.f), 1.f);
        float a1 = fminf(fmaxf(h1 + bias[2 * k + 1], 0.f), 1.f);
        dot += a0 * wo[2 * k] + a1 * wo[2 * k + 1];
    }

#pragma unroll
    for (int off = 32; off > 0; off >>= 1)
        dot += __shfl_xor(dot, off, 64);

    if (lane == 0)
        out[b] = 1.f / (1.f + expf(-(dot + b_out[0])));
}

extern "C" void kernel_launch(void* const* d_in, const int* in_sizes, int n_in,
                              void* d_out, int out_size, void* d_ws, size_t ws_size,
                              hipStream_t stream) {
    const int*   stm_idx  = (const int*)  d_in[0];
    const int*   nstm_idx = (const int*)  d_in[1];
    const float* stm_val  = (const float*)d_in[2];
    const float* nstm_val = (const float*)d_in[3];
    const float* W_ft     = (const float*)d_in[5];
    const float* b_ft     = (const float*)d_in[6];
    const float* W_out    = (const float*)d_in[7];
    const float* b_out    = (const float*)d_in[8];
    float*       out      = (float*)d_out;
    uchar*       Wt8      = (uchar*)d_ws;   // 384 KiB

    dim3 tb(32, 8);
    dim3 tg(F_DIM / 32, H_DIM / 32);
    transpose_convert<<<tg, tb, 0, stream>>>(W_ft, Wt8);

    nnue_fwd<<<B_SZ / 4, 256, 0, stream>>>(stm_idx, nstm_idx, stm_val, nstm_val,
                                           Wt8, b_ft, W_out, b_out, out);
}